// Round 1
// baseline (434.820 us; speedup 1.0000x reference)
//
#include <hip/hip_runtime.h>
#include <hip/hip_bf16.h>

// out[b,p,c] = sum_s x[b,s,c] * W[c,p,s] + bias[c,p]
// x: [64,720,321] f32, W: [321,720,720] f32, bias: [321,720] f32, out: [64,720,321] f32
// Strategy: HBM-bound streaming problem (W=666MB read once). bf16 MFMA makes compute free.
// Kernel 1: transpose x -> Xt[C][B][S] bf16 in workspace (coalesced GEMM A-loads).
// Kernel 2: per-channel GEMM M=64,N=144-tile,K=720. No LDS, no barriers; waves own
//           disjoint N ranges so W is fetched exactly once. XCD-grouped block order so
//           the 16 channel-blocks sharing each output cacheline merge writes in one L2.

#define SEQ   720
#define PRED  720
#define CH    321
#define BATCH 64
#define RTOT  (BATCH*SEQ)      /* 46080 rows of the 2D view x[r][c] */
#define BN    144              /* P-tile: 720 = 5*144, no N tail */
#define NTILE 5
#define NCHUNK 21              /* ceil(321/16) channel chunks (one out-cacheline) */
#define NGROUP (NCHUNK*NTILE)  /* 105 groups of 16 blocks */

typedef __attribute__((ext_vector_type(8))) short short8;
typedef __attribute__((ext_vector_type(4))) float f32x4;

__device__ __forceinline__ short bf16bits(float f) {
    return __builtin_bit_cast(short, __float2bfloat16(f));
}

// ---------------- x transpose: [46080][321] f32 -> [321][46080] bf16 ----------------
__global__ __launch_bounds__(256) void xpose_kernel(const float* __restrict__ x,
                                                    unsigned short* __restrict__ xt) {
    __shared__ float tile[64][33];  // +1 pad: conflict-free transposed read
    const int bid = blockIdx.x;
    const int rt = bid % (RTOT/64);
    const int ct = bid / (RTOT/64);
    const int r0 = rt*64, c0 = ct*32;
    const int t  = threadIdx.x;
    const int cl = t & 31, rl0 = t >> 5;
    const int cg = c0 + cl;
    if (cg < CH) {
#pragma unroll
        for (int j = 0; j < 8; ++j) {
            int rl = rl0 + j*8;
            tile[rl][cl] = x[(size_t)(r0+rl)*CH + cg];   // coalesced along c
        }
    }
    __syncthreads();
#pragma unroll
    for (int j = 0; j < 8; ++j) {
        int idx = t + j*256;
        int c_l = idx >> 6;      // 0..31
        int r_l = idx & 63;      // consecutive lanes -> consecutive r: coalesced
        if (c0 + c_l < CH)
            xt[(size_t)(c0+c_l)*RTOT + r0 + r_l] = (unsigned short)bf16bits(tile[r_l][c_l]);
    }
}

// ---------------- per-channel GEMM ----------------
// block: 192 thr (3 waves). wave w: M=64 x N=48 (4x3 frags of 16x16x32 bf16 MFMA).
// USE_XT=false fallback gathers A straight from x (only if ws too small).
template<bool USE_XT>
__global__ __launch_bounds__(192) void gemm_kernel(
        const float* __restrict__ W, const float* __restrict__ bias,
        const unsigned short* __restrict__ xt, const float* __restrict__ x,
        float* __restrict__ out) {
    // Block -> (channel, p-tile) mapping. Groups of 16 consecutive channels (one
    // 64B out line) x same p-tile are placed on consecutive slots of ONE XCD
    // (dispatch assumed round-robin: xcd = blockIdx % 8) so partial line writes
    // merge in that XCD's L2. Groups round-robin over XCDs for balance.
    const int bid  = blockIdx.x;
    const int xcd  = bid & 7;
    const int rest = bid >> 3;
    const int gi   = rest >> 4;
    const int coff = rest & 15;
    const int g    = xcd + 8*gi;
    if (g >= NGROUP) return;
    const int chunk = g % NCHUNK;
    const int pt    = g / NCHUNK;
    const int c     = chunk*16 + coff;
    if (c >= CH) return;
    const int p0 = pt * BN;

    const int tid  = threadIdx.x;
    const int wv   = tid >> 6;
    const int lane = tid & 63;
    const int row  = lane & 15;   // A: M-row / B: N-col / store: p-col
    const int kch  = lane >> 4;   // k-chunk (8 elems each)
    const int nb   = p0 + wv*48;  // this wave's N base (disjoint W rows -> W read once)

    const float* Wc          = W  + (size_t)c * ((size_t)PRED * SEQ);
    const unsigned short* Xc = xt + (size_t)c * RTOT;

    f32x4 acc[4][3] = {};

    short8 A0[4], A1[4], B0[3], B1[3];
    f32x4 brlo[3], brhi[3];

    auto load_a = [&](short8 (&A)[4], int s, int kc) {
        if (USE_XT) {
#pragma unroll
            for (int mi = 0; mi < 4; ++mi)
                A[mi] = *reinterpret_cast<const short8*>(
                          Xc + (size_t)(mi*16 + row)*SEQ + s + kc*8);
        } else {
#pragma unroll
            for (int mi = 0; mi < 4; ++mi) {
                short8 v;
#pragma unroll
                for (int j = 0; j < 8; ++j)
                    v[j] = bf16bits(x[((size_t)(mi*16 + row)*SEQ + s + kc*8 + j)*CH + c]);
                A[mi] = v;
            }
        }
    };
    auto load_b = [&](int s, int kc) {
#pragma unroll
        for (int ni = 0; ni < 3; ++ni) {
            const float* p = Wc + (size_t)(nb + ni*16 + row)*SEQ + s + kc*8;
            brlo[ni] = *reinterpret_cast<const f32x4*>(p);
            brhi[ni] = *reinterpret_cast<const f32x4*>(p + 4);
        }
    };
    auto cvt_b = [&](short8 (&B)[3]) {
#pragma unroll
        for (int ni = 0; ni < 3; ++ni) {
            short8 v;
#pragma unroll
            for (int j = 0; j < 4; ++j) { v[j] = bf16bits(brlo[ni][j]); v[4+j] = bf16bits(brhi[ni][j]); }
            B[ni] = v;
        }
    };
    auto mfma_all = [&](short8 (&A)[4], short8 (&B)[3]) {
#pragma unroll
        for (int mi = 0; mi < 4; ++mi)
#pragma unroll
            for (int ni = 0; ni < 3; ++ni)
                acc[mi][ni] = __builtin_amdgcn_mfma_f32_16x16x32_bf16(
                                  A[mi], B[ni], acc[mi][ni], 0, 0, 0);
    };

    // K = 720 = 22 full steps of 32 + one reg-zero-padded tail of 16.
    // Depth-1 register pipeline: prefetch step k+1, MFMA step k.
    load_a(A0, 0, kch);
    load_b(0, kch);
    cvt_b(B0);
    for (int k2 = 0; k2 < 11; ++k2) {
        const int s1 = k2*64 + 32;
        load_a(A1, s1, kch);
        load_b(s1, kch);
        mfma_all(A0, B0);       // step s1-32, latency of s1 loads hides under it
        cvt_b(B1);
        const int s2 = s1 + 32;
        if (s2 < 704) {
            load_a(A0, s2, kch);
            load_b(s2, kch);
        }
        mfma_all(A1, B1);       // step s1
        if (s2 < 704) cvt_b(B0);
    }
    {   // tail: s in [704,720). k-chunks 2,3 are out of range -> zero their frags.
        const int kc = kch & 1;
        load_a(A1, 704, kc);
        load_b(704, kc);
        cvt_b(B1);
        if (kch >= 2) {
            short8 z = {};
#pragma unroll
            for (int mi = 0; mi < 4; ++mi) A1[mi] = z;
#pragma unroll
            for (int ni = 0; ni < 3; ++ni) B1[ni] = z;
        }
        mfma_all(A1, B1);
    }

    // Epilogue: C/D map (verified m89/m91): col = lane&15, row = (lane>>4)*4 + reg.
    const int col   = lane & 15;
    const int rquad = lane >> 4;
#pragma unroll
    for (int ni = 0; ni < 3; ++ni) {
        const int p = nb + ni*16 + col;
        const float bv = bias[(size_t)c*PRED + p];
#pragma unroll
        for (int mi = 0; mi < 4; ++mi) {
#pragma unroll
            for (int r = 0; r < 4; ++r) {
                const int b = mi*16 + rquad*4 + r;
                out[((size_t)b*PRED + p)*CH + c] = acc[mi][ni][r] + bv;
            }
        }
    }
}

extern "C" void kernel_launch(void* const* d_in, const int* in_sizes, int n_in,
                              void* d_out, int out_size, void* d_ws, size_t ws_size,
                              hipStream_t stream) {
    const float* x    = (const float*)d_in[0];
    const float* W    = (const float*)d_in[1];
    const float* bias = (const float*)d_in[2];
    float* out        = (float*)d_out;

    const size_t xt_bytes = (size_t)CH * RTOT * sizeof(unsigned short); // 29.6 MB
    const int gemm_blocks = 8 * 14 * 16;  // covers 105 groups x 16 blocks (+dead pad)

    if (ws_size >= xt_bytes) {
        unsigned short* xt = (unsigned short*)d_ws;
        xpose_kernel<<<dim3((RTOT/64) * 11), dim3(256), 0, stream>>>(x, xt);
        gemm_kernel<true><<<dim3(gemm_blocks), dim3(192), 0, stream>>>(W, bias, xt, x, out);
    } else {
        // workspace too small: gather A directly from x (slower, still correct)
        gemm_kernel<false><<<dim3(gemm_blocks), dim3(192), 0, stream>>>(W, bias, nullptr, x, out);
    }
}

// Round 2
// 288.363 us; speedup vs baseline: 1.5079x; 1.5079x over previous
//
#include <hip/hip_runtime.h>
#include <hip/hip_bf16.h>

// out[b,p,c] = sum_s x[b,s,c] * W[c,p,s] + bias[c,p]
// x: [64,720,321] f32, W: [321,720,720] f32, bias: [321,720] f32, out: [64,720,321] f32
// R2: (1) staged output stage[C][P][B] (coalesced stores) + LDS-transpose kernel,
//     (2) 2-deep register pipeline with counted waits (cvt(k) -> mfma(k) -> issue(k+2)).

#define SEQ   720
#define PRED  720
#define CH    321
#define BATCH 64
#define RTOT  (BATCH*SEQ)      /* 46080 rows of the 2D view x[r][c] */
#define BN    144              /* P-tile: 720 = 5*144 */
#define NTILE 5
#define NCHUNK 21
#define NGROUP (NCHUNK*NTILE)  /* 105 groups of 16 blocks */

typedef __attribute__((ext_vector_type(8))) short short8;
typedef __attribute__((ext_vector_type(4))) float f32x4;

__device__ __forceinline__ short bf16bits(float f) {
    return __builtin_bit_cast(short, __float2bfloat16(f));
}

// ---------------- x transpose: [46080][321] f32 -> [321][46080] bf16 ----------------
__global__ __launch_bounds__(256) void xpose_kernel(const float* __restrict__ x,
                                                    unsigned short* __restrict__ xt) {
    __shared__ float tile[64][33];
    const int bid = blockIdx.x;
    const int rt = bid % (RTOT/64);
    const int ct = bid / (RTOT/64);
    const int r0 = rt*64, c0 = ct*32;
    const int t  = threadIdx.x;
    const int cl = t & 31, rl0 = t >> 5;
    const int cg = c0 + cl;
    if (cg < CH) {
#pragma unroll
        for (int j = 0; j < 8; ++j) {
            int rl = rl0 + j*8;
            tile[rl][cl] = x[(size_t)(r0+rl)*CH + cg];
        }
    }
    __syncthreads();
#pragma unroll
    for (int j = 0; j < 8; ++j) {
        int idx = t + j*256;
        int c_l = idx >> 6;
        int r_l = idx & 63;
        if (c0 + c_l < CH)
            xt[(size_t)(c0+c_l)*RTOT + r0 + r_l] = (unsigned short)bf16bits(tile[r_l][c_l]);
    }
}

// ---------------- per-channel GEMM ----------------
// block: 192 thr (3 waves). wave: M=64 x N=48 (4x3 frags of 16x16x32 bf16 MFMA).
// STAGED: write stage[c][p][b] f32 (coalesced); else direct scattered store to out.
template<bool USE_XT, bool STAGED>
__global__ __launch_bounds__(192) void gemm_kernel(
        const float* __restrict__ W, const float* __restrict__ bias,
        const unsigned short* __restrict__ xt, const float* __restrict__ x,
        float* __restrict__ outp) {
    const int bid  = blockIdx.x;
    const int xcd  = bid & 7;
    const int rest = bid >> 3;
    const int gi   = rest >> 4;
    const int coff = rest & 15;
    const int g    = xcd + 8*gi;
    if (g >= NGROUP) return;
    const int chunk = g % NCHUNK;
    const int pt    = g / NCHUNK;
    const int c     = chunk*16 + coff;
    if (c >= CH) return;
    const int p0 = pt * BN;

    const int tid  = threadIdx.x;
    const int wv   = tid >> 6;
    const int lane = tid & 63;
    const int row  = lane & 15;   // A: M-row / B: N-row
    const int kch  = lane >> 4;   // k-chunk (8 elems each)
    const int nb   = p0 + wv*48;  // wave's N base: disjoint W rows -> W read once

    const float* Wc          = W  + (size_t)c * ((size_t)PRED * SEQ);
    const unsigned short* Xc = xt + (size_t)c * RTOT;

    f32x4 acc[4][3] = {};
    short8 A[2][4];
    f32x4 BL[2][3], BH[2][3];

    auto issue = [&](int buf, int k) {
        const int kc = (k == 22) ? (kch & 1) : kch;  // tail: clamp to valid K range
        const int s  = k*32 + kc*8;
        if (USE_XT) {
#pragma unroll
            for (int mi = 0; mi < 4; ++mi)
                A[buf][mi] = *reinterpret_cast<const short8*>(
                              Xc + (size_t)(mi*16 + row)*SEQ + s);
        } else {
#pragma unroll
            for (int mi = 0; mi < 4; ++mi) {
                short8 v;
#pragma unroll
                for (int j = 0; j < 8; ++j)
                    v[j] = bf16bits(x[((size_t)(mi*16 + row)*SEQ + s + j)*CH + c]);
                A[buf][mi] = v;
            }
        }
#pragma unroll
        for (int ni = 0; ni < 3; ++ni) {
            const float* p = Wc + (size_t)(nb + ni*16 + row)*SEQ + s;
            BL[buf][ni] = *reinterpret_cast<const f32x4*>(p);
            BH[buf][ni] = *reinterpret_cast<const f32x4*>(p + 4);
        }
    };

    // K = 720: 22 full steps of 32 + one tail step of 16 (lanes kch>=2 zeroed via B).
    issue(0, 0);
    issue(1, 1);
#pragma unroll
    for (int k = 0; k < 23; ++k) {
        const int buf = k & 1;
        short8 Bb[3];
#pragma unroll
        for (int ni = 0; ni < 3; ++ni) {
            short8 v;
#pragma unroll
            for (int j = 0; j < 4; ++j) {
                v[j]   = bf16bits(BL[buf][ni][j]);   // waits: counted vmcnt (k+1 in flight)
                v[4+j] = bf16bits(BH[buf][ni][j]);
            }
            Bb[ni] = v;
        }
        if (k == 22 && kch >= 2) {
            short8 z = {};
#pragma unroll
            for (int ni = 0; ni < 3; ++ni) Bb[ni] = z;   // zero k=16..31 contribution
        }
#pragma unroll
        for (int mi = 0; mi < 4; ++mi)
#pragma unroll
            for (int ni = 0; ni < 3; ++ni)
                acc[mi][ni] = __builtin_amdgcn_mfma_f32_16x16x32_bf16(
                                  A[buf][mi], Bb[ni], acc[mi][ni], 0, 0, 0);
        if (k + 2 < 23) issue(buf, k + 2);   // after MFMA consumed A[buf] (WAR-safe)
    }

    // Epilogue. C/D map: col = lane&15, row = (lane>>4)*4 + reg.
    const int col   = lane & 15;
    const int rquad = lane >> 4;
    if (STAGED) {
#pragma unroll
        for (int ni = 0; ni < 3; ++ni) {
            const int p = nb + ni*16 + col;
            const float bv = bias[(size_t)c*PRED + p];
#pragma unroll
            for (int mi = 0; mi < 4; ++mi) {
                f32x4 v = acc[mi][ni];
#pragma unroll
                for (int r = 0; r < 4; ++r) v[r] += bv;
                *reinterpret_cast<f32x4*>(
                    outp + ((size_t)c*PRED + p)*BATCH + mi*16 + rquad*4) = v;
            }
        }
    } else {
#pragma unroll
        for (int ni = 0; ni < 3; ++ni) {
            const int p = nb + ni*16 + col;
            const float bv = bias[(size_t)c*PRED + p];
#pragma unroll
            for (int mi = 0; mi < 4; ++mi)
#pragma unroll
                for (int r = 0; r < 4; ++r) {
                    const int b = mi*16 + rquad*4 + r;
                    outp[((size_t)b*PRED + p)*CH + c] = acc[mi][ni][r] + bv;
                }
        }
    }
}

// ---------------- unstage: stage[C][P][B] -> out[B][P][C] ----------------
// block per (p, c-tile of 128). All-scalar, conflict-free [128][65] LDS tile,
// coalesced global reads (b contiguous) and writes (c contiguous).
__global__ __launch_bounds__(256) void unstage_kernel(const float* __restrict__ stage,
                                                      float* __restrict__ out) {
    const int p  = blockIdx.x;
    const int c0 = blockIdx.y * 128;
    const int cn = (CH - c0 < 128) ? (CH - c0) : 128;
    __shared__ float tl[128][65];
    const int t = threadIdx.x;
    {
        const int b   = t & 63;
        const int ci0 = t >> 6;
        for (int ci = ci0; ci < cn; ci += 4)
            tl[ci][b] = stage[((size_t)(c0+ci)*PRED + p)*BATCH + b];
    }
    __syncthreads();
    {
        const int cl = t & 127;
        const int b0 = t >> 7;
        if (cl < cn)
#pragma unroll
            for (int bb = b0; bb < BATCH; bb += 2)
                out[((size_t)bb*PRED + p)*CH + c0 + cl] = tl[cl][bb];
    }
}

extern "C" void kernel_launch(void* const* d_in, const int* in_sizes, int n_in,
                              void* d_out, int out_size, void* d_ws, size_t ws_size,
                              hipStream_t stream) {
    const float* x    = (const float*)d_in[0];
    const float* W    = (const float*)d_in[1];
    const float* bias = (const float*)d_in[2];
    float* out        = (float*)d_out;

    const size_t xt_bytes    = (size_t)CH * RTOT * sizeof(unsigned short);   // 29.6 MB
    const size_t stage_bytes = (size_t)CH * PRED * BATCH * sizeof(float);    // 59.2 MB
    const int gemm_blocks = 8 * 14 * 16;  // covers 105 groups x 16 blocks (+dead pad)

    if (ws_size >= xt_bytes + stage_bytes) {
        unsigned short* xtp = (unsigned short*)d_ws;
        float* stage = (float*)((char*)d_ws + xt_bytes);   // 16B-aligned (29583360%16==0)
        xpose_kernel<<<dim3((RTOT/64) * 11), dim3(256), 0, stream>>>(x, xtp);
        gemm_kernel<true, true><<<dim3(gemm_blocks), dim3(192), 0, stream>>>(
            W, bias, xtp, x, stage);
        unstage_kernel<<<dim3(PRED, 3), dim3(256), 0, stream>>>(stage, out);
    } else if (ws_size >= xt_bytes) {
        unsigned short* xtp = (unsigned short*)d_ws;
        xpose_kernel<<<dim3((RTOT/64) * 11), dim3(256), 0, stream>>>(x, xtp);
        gemm_kernel<true, false><<<dim3(gemm_blocks), dim3(192), 0, stream>>>(
            W, bias, xtp, x, out);
    } else {
        gemm_kernel<false, false><<<dim3(gemm_blocks), dim3(192), 0, stream>>>(
            W, bias, nullptr, x, out);
    }
}

// Round 3
// 233.368 us; speedup vs baseline: 1.8632x; 1.2357x over previous
//
#include <hip/hip_runtime.h>
#include <hip/hip_bf16.h>

// out[b,p,c] = sum_s x[b,s,c] * W[c,p,s] + bias[c,p]
// x: [64,720,321] f32, W: [321,720,720] f32, bias: [321,720] f32, out: [64,720,321] f32
// R3: m97-structure GEMM — global_load_lds prefetch (compiler can't sink it),
//     double-buffered LDS (B f32 [144][32] XOR-swizzled, A bf16 [64][32] XOR-swizzled),
//     one barrier pair per K-step. Staged output + unstage transpose kept from R2.

#define SEQ   720
#define PRED  720
#define CH    321
#define BATCH 64
#define RTOT  (BATCH*SEQ)
#define BN    144
#define NTILE 5
#define NCHUNK 21
#define NGROUP (NCHUNK*NTILE)   /* 105 groups of 16 blocks */

typedef __attribute__((ext_vector_type(8))) short short8;
typedef __attribute__((ext_vector_type(4))) float f32x4;
typedef unsigned int u32;

__device__ __forceinline__ short bf16bits(float f) {
    return __builtin_bit_cast(short, __float2bfloat16(f));
}

// async global->LDS DMA, 16B per lane. Dest must be wave-uniform base (+lane*16 by HW).
__device__ __forceinline__ void gload16(const void* g, void* l) {
    __builtin_amdgcn_global_load_lds((const __attribute__((address_space(1))) u32*)g,
                                     (__attribute__((address_space(3))) u32*)l, 16, 0, 0);
}

// ---------------- x transpose: [46080][321] f32 -> [321][46080] bf16 ----------------
__global__ __launch_bounds__(256) void xpose_kernel(const float* __restrict__ x,
                                                    unsigned short* __restrict__ xt) {
    __shared__ float tile[64][33];
    const int bid = blockIdx.x;
    const int rt = bid % (RTOT/64);
    const int ct = bid / (RTOT/64);
    const int r0 = rt*64, c0 = ct*32;
    const int t  = threadIdx.x;
    const int cl = t & 31, rl0 = t >> 5;
    const int cg = c0 + cl;
    if (cg < CH) {
#pragma unroll
        for (int j = 0; j < 8; ++j) {
            int rl = rl0 + j*8;
            tile[rl][cl] = x[(size_t)(r0+rl)*CH + cg];
        }
    }
    __syncthreads();
#pragma unroll
    for (int j = 0; j < 8; ++j) {
        int idx = t + j*256;
        int c_l = idx >> 6;
        int r_l = idx & 63;
        if (c0 + c_l < CH)
            xt[(size_t)(c0+c_l)*RTOT + r0 + r_l] = (unsigned short)bf16bits(tile[r_l][c_l]);
    }
}

// ---------------- per-channel GEMM, LDS double-buffered (m97 structure) ----------------
// block: 192 thr (3 waves), one (channel, p-tile of 144). wave: M=64 x N=48.
// LDS B: [144 rows][8 chunks of 16B] f32, physical chunk q holds source chunk q^(row&7).
// LDS A: [64 rows][4 chunks of 16B] bf16, physical chunk q holds source chunk q^(row&3).
template<bool STAGED>
__global__ __launch_bounds__(192) void gemm_lds_kernel(
        const float* __restrict__ W, const float* __restrict__ bias,
        const unsigned short* __restrict__ xt, float* __restrict__ outp) {
    __shared__ __align__(16) float          Bl[2][BN*32];   // 2 x 18432 B
    __shared__ __align__(16) unsigned short Al[2][64*32];   // 2 x  4096 B

    const int bid  = blockIdx.x;
    const int xcd  = bid & 7;
    const int rest = bid >> 3;
    const int gi   = rest >> 4;
    const int coff = rest & 15;
    const int g    = xcd + 8*gi;
    if (g >= NGROUP) return;
    const int chunk = g % NCHUNK;
    const int pt    = g / NCHUNK;
    const int c     = chunk*16 + coff;
    if (c >= CH) return;
    const int p0 = pt * BN;

    const int tid  = threadIdx.x;
    const int wv   = tid >> 6;
    const int lane = tid & 63;
    const int row  = lane & 15;
    const int kch  = lane >> 4;
    const int nb   = p0 + wv*48;

    const float* Wc          = W  + (size_t)c * ((size_t)PRED * SEQ);
    const unsigned short* Xc = xt + (size_t)c * RTOT;

    // ---- staging (global source per-lane w/ inverse swizzle; LDS dest linear) ----
    auto stageB = [&](int buf, int k) {
#pragma unroll
        for (int i = 0; i < 6; ++i) {
            const int slot = i*192 + tid;
            const int r    = slot >> 3;        // 0..143
            int sc = (slot & 7) ^ (r & 7);     // source 16B chunk
            if (k == 22) sc &= 3;              // tail: clamp to valid s<720 (finite)
            gload16(Wc + (size_t)(p0 + r)*SEQ + k*32 + sc*4,
                    &Bl[buf][(size_t)(i*192 + (tid & ~63)) * 4]);
        }
    };
    auto stageA = [&](int buf, int k) {
        {
            const int r = tid >> 2;            // 0..47
            int sc = (tid & 3) ^ (r & 3);
            if (k == 22) sc &= 1;
            gload16(Xc + (size_t)r*SEQ + k*32 + sc*8,
                    &Al[buf][(size_t)(tid & ~63) * 8]);
        }
        if (tid < 64) {
            const int slot = 192 + tid;
            const int r    = slot >> 2;        // 48..63
            int sc = (slot & 3) ^ (r & 3);
            if (k == 22) sc &= 1;
            gload16(Xc + (size_t)r*SEQ + k*32 + sc*8,
                    &Al[buf][(size_t)192 * 8]);
        }
    };

    f32x4 acc[4][3] = {};

    stageB(0, 0);
    stageA(0, 0);
    __syncthreads();   // drains vmcnt(0): buf0 ready

    for (int k = 0; k < 23; ++k) {
        const int buf = k & 1;
        if (k < 22) { stageB(buf ^ 1, k + 1); stageA(buf ^ 1, k + 1); }  // async, in flight

        short8 Af[4];
#pragma unroll
        for (int mi = 0; mi < 4; ++mi) {
            const int r2 = mi*16 + row;
            const int qa = kch ^ (r2 & 3);
            Af[mi] = *reinterpret_cast<const short8*>(&Al[buf][r2*32 + qa*8]);
        }
        short8 Bf[3];
#pragma unroll
        for (int ni = 0; ni < 3; ++ni) {
            const int r2  = wv*48 + ni*16 + row;
            const int qlo = (2*kch)     ^ (r2 & 7);
            const int qhi = (2*kch + 1) ^ (r2 & 7);
            f32x4 lo = *reinterpret_cast<const f32x4*>(&Bl[buf][r2*32 + qlo*4]);
            f32x4 hi = *reinterpret_cast<const f32x4*>(&Bl[buf][r2*32 + qhi*4]);
            short8 v;
#pragma unroll
            for (int j = 0; j < 4; ++j) { v[j] = bf16bits(lo[j]); v[4+j] = bf16bits(hi[j]); }
            Bf[ni] = v;
        }
        if (k == 22 && kch >= 2) {     // zero invalid K range (clamped data is finite)
            short8 z = {};
            Bf[0] = z; Bf[1] = z; Bf[2] = z;
        }
#pragma unroll
        for (int mi = 0; mi < 4; ++mi)
#pragma unroll
            for (int ni = 0; ni < 3; ++ni)
                acc[mi][ni] = __builtin_amdgcn_mfma_f32_16x16x32_bf16(
                                  Af[mi], Bf[ni], acc[mi][ni], 0, 0, 0);
        __syncthreads();   // next staging done + safe to overwrite buf next iter
    }

    // Epilogue. C/D map: col = lane&15, row = (lane>>4)*4 + reg.
    const int col   = lane & 15;
    const int rquad = lane >> 4;
    if (STAGED) {
#pragma unroll
        for (int ni = 0; ni < 3; ++ni) {
            const int p = nb + ni*16 + col;
            const float bv = bias[(size_t)c*PRED + p];
#pragma unroll
            for (int mi = 0; mi < 4; ++mi) {
                f32x4 v = acc[mi][ni];
#pragma unroll
                for (int r = 0; r < 4; ++r) v[r] += bv;
                *reinterpret_cast<f32x4*>(
                    outp + ((size_t)c*PRED + p)*BATCH + mi*16 + rquad*4) = v;
            }
        }
    } else {
#pragma unroll
        for (int ni = 0; ni < 3; ++ni) {
            const int p = nb + ni*16 + col;
            const float bv = bias[(size_t)c*PRED + p];
#pragma unroll
            for (int mi = 0; mi < 4; ++mi)
#pragma unroll
                for (int r = 0; r < 4; ++r) {
                    const int b = mi*16 + rquad*4 + r;
                    outp[((size_t)b*PRED + p)*CH + c] = acc[mi][ni][r] + bv;
                }
        }
    }
}

// ---------------- fallback (no workspace): gather x directly, scattered stores ----------------
__global__ __launch_bounds__(192) void gemm_fallback_kernel(
        const float* __restrict__ W, const float* __restrict__ bias,
        const float* __restrict__ x, float* __restrict__ outp) {
    const int bid  = blockIdx.x;
    const int g    = (bid & 7) + 8*((bid >> 3) >> 4);
    const int coff = (bid >> 3) & 15;
    if (g >= NGROUP) return;
    const int c  = (g % NCHUNK)*16 + coff;
    if (c >= CH) return;
    const int p0 = (g / NCHUNK) * BN;
    const int tid = threadIdx.x, wv = tid >> 6, lane = tid & 63;
    const int row = lane & 15, kch = lane >> 4, nb = p0 + wv*48;
    const float* Wc = W + (size_t)c * ((size_t)PRED * SEQ);
    f32x4 acc[4][3] = {};
    for (int k = 0; k < 23; ++k) {
        const int kc = (k == 22) ? (kch & 1) : kch;
        const int s  = k*32 + kc*8;
        short8 Af[4], Bf[3];
#pragma unroll
        for (int mi = 0; mi < 4; ++mi) {
            short8 v;
#pragma unroll
            for (int j = 0; j < 8; ++j)
                v[j] = bf16bits(x[((size_t)(mi*16 + row)*SEQ + s + j)*CH + c]);
            Af[mi] = v;
        }
#pragma unroll
        for (int ni = 0; ni < 3; ++ni) {
            const float* p = Wc + (size_t)(nb + ni*16 + row)*SEQ + s;
            short8 v;
#pragma unroll
            for (int j = 0; j < 4; ++j) { v[j] = bf16bits(p[j]); v[4+j] = bf16bits(p[4+j]); }
            Bf[ni] = v;
        }
        if (k == 22 && kch >= 2) { short8 z = {}; Bf[0] = z; Bf[1] = z; Bf[2] = z; }
#pragma unroll
        for (int mi = 0; mi < 4; ++mi)
#pragma unroll
            for (int ni = 0; ni < 3; ++ni)
                acc[mi][ni] = __builtin_amdgcn_mfma_f32_16x16x32_bf16(
                                  Af[mi], Bf[ni], acc[mi][ni], 0, 0, 0);
    }
    const int col = lane & 15, rquad = lane >> 4;
#pragma unroll
    for (int ni = 0; ni < 3; ++ni) {
        const int p = nb + ni*16 + col;
        const float bv = bias[(size_t)c*PRED + p];
#pragma unroll
        for (int mi = 0; mi < 4; ++mi)
#pragma unroll
            for (int r = 0; r < 4; ++r)
                outp[((size_t)(mi*16 + rquad*4 + r)*PRED + p)*CH + c] = acc[mi][ni][r] + bv;
    }
}

// ---------------- unstage: stage[C][P][B] -> out[B][P][C] ----------------
__global__ __launch_bounds__(256) void unstage_kernel(const float* __restrict__ stage,
                                                      float* __restrict__ out) {
    const int p  = blockIdx.x;
    const int c0 = blockIdx.y * 128;
    const int cn = (CH - c0 < 128) ? (CH - c0) : 128;
    __shared__ float tl[128][65];
    const int t = threadIdx.x;
    {
        const int b   = t & 63;
        const int ci0 = t >> 6;
        for (int ci = ci0; ci < cn; ci += 4)
            tl[ci][b] = stage[((size_t)(c0+ci)*PRED + p)*BATCH + b];
    }
    __syncthreads();
    {
        const int cl = t & 127;
        const int b0 = t >> 7;
        if (cl < cn)
#pragma unroll
            for (int bb = b0; bb < BATCH; bb += 2)
                out[((size_t)bb*PRED + p)*CH + c0 + cl] = tl[cl][bb];
    }
}

extern "C" void kernel_launch(void* const* d_in, const int* in_sizes, int n_in,
                              void* d_out, int out_size, void* d_ws, size_t ws_size,
                              hipStream_t stream) {
    const float* x    = (const float*)d_in[0];
    const float* W    = (const float*)d_in[1];
    const float* bias = (const float*)d_in[2];
    float* out        = (float*)d_out;

    const size_t xt_bytes    = (size_t)CH * RTOT * sizeof(unsigned short);   // 29.6 MB
    const size_t stage_bytes = (size_t)CH * PRED * BATCH * sizeof(float);    // 59.2 MB
    const int gemm_blocks = 8 * 14 * 16;  // covers 105 groups x 16 blocks (+dead pad)

    if (ws_size >= xt_bytes + stage_bytes) {
        unsigned short* xtp = (unsigned short*)d_ws;
        float* stage = (float*)((char*)d_ws + xt_bytes);
        xpose_kernel<<<dim3((RTOT/64) * 11), dim3(256), 0, stream>>>(x, xtp);
        gemm_lds_kernel<true><<<dim3(gemm_blocks), dim3(192), 0, stream>>>(
            W, bias, xtp, stage);
        unstage_kernel<<<dim3(PRED, 3), dim3(256), 0, stream>>>(stage, out);
    } else if (ws_size >= xt_bytes) {
        unsigned short* xtp = (unsigned short*)d_ws;
        xpose_kernel<<<dim3((RTOT/64) * 11), dim3(256), 0, stream>>>(x, xtp);
        gemm_lds_kernel<false><<<dim3(gemm_blocks), dim3(192), 0, stream>>>(
            W, bias, xtp, out);
    } else {
        gemm_fallback_kernel<<<dim3(gemm_blocks), dim3(192), 0, stream>>>(
            W, bias, x, out);
    }
}

// Round 4
// 225.211 us; speedup vs baseline: 1.9307x; 1.0362x over previous
//
#include <hip/hip_runtime.h>
#include <hip/hip_bf16.h>

// out[b,p,c] = sum_s x[b,s,c] * W[c,p,s] + bias[c,p]
// x: [64,720,321] f32, W: [321,720,720] f32, bias: [321,720] f32, out: [64,720,321] f32
// R4: counted-vmcnt double-buffer pipeline (never drain to 0 in main loop) + raw
//     s_barrier; uniform 8 DMA instrs/wave/K-step. bf16 staging buffer (halves
//     stage traffic). xpose + unstage transpose kept.

#define SEQ   720
#define PRED  720
#define CH    321
#define BATCH 64
#define RTOT  (BATCH*SEQ)
#define BN    144
#define NTILE 5
#define NCHUNK 21
#define NGROUP (NCHUNK*NTILE)   /* 105 groups of 16 blocks */

typedef __attribute__((ext_vector_type(8))) short short8;
typedef __attribute__((ext_vector_type(4))) float f32x4;
typedef __attribute__((ext_vector_type(4))) unsigned short us4;
typedef unsigned int u32;

__device__ __forceinline__ short bf16bits(float f) {
    return __builtin_bit_cast(short, __float2bfloat16(f));
}

// async global->LDS DMA, 16B per lane. LDS dest is wave-uniform base (+lane*16 by HW).
__device__ __forceinline__ void gload16(const void* g, void* l) {
    __builtin_amdgcn_global_load_lds((const __attribute__((address_space(1))) u32*)g,
                                     (__attribute__((address_space(3))) u32*)l, 16, 0, 0);
}

// ---------------- x transpose: [46080][321] f32 -> [321][46080] bf16 ----------------
__global__ __launch_bounds__(256) void xpose_kernel(const float* __restrict__ x,
                                                    unsigned short* __restrict__ xt) {
    __shared__ float tile[64][33];
    const int bid = blockIdx.x;
    const int rt = bid % (RTOT/64);
    const int ct = bid / (RTOT/64);
    const int r0 = rt*64, c0 = ct*32;
    const int t  = threadIdx.x;
    const int cl = t & 31, rl0 = t >> 5;
    const int cg = c0 + cl;
    if (cg < CH) {
#pragma unroll
        for (int j = 0; j < 8; ++j) {
            int rl = rl0 + j*8;
            tile[rl][cl] = x[(size_t)(r0+rl)*CH + cg];
        }
    }
    __syncthreads();
#pragma unroll
    for (int j = 0; j < 8; ++j) {
        int idx = t + j*256;
        int c_l = idx >> 6;
        int r_l = idx & 63;
        if (c0 + c_l < CH)
            xt[(size_t)(c0+c_l)*RTOT + r0 + r_l] = (unsigned short)bf16bits(tile[r_l][c_l]);
    }
}

// ---------------- per-channel GEMM, counted-vmcnt double-buffered ----------------
// block: 192 thr (3 waves), one (channel, p-tile of 144). wave: M=64 x N=48.
// LDS B: [144][8 x 16B] f32, phys chunk q of row r holds source chunk q^(r&7).
// LDS A: [64][4 x 16B] bf16, phys chunk q of row r holds source chunk q^(r&3).
// Staging = exactly 8 gload16 per wave (6 B + 2 A; A pads via benign duplicates).
template<bool STAGED>
__global__ __launch_bounds__(192) void gemm_lds_kernel(
        const float* __restrict__ W, const float* __restrict__ bias,
        const unsigned short* __restrict__ xt, void* __restrict__ outp) {
    __shared__ __align__(16) float          Bl[2][BN*32];   // 2 x 18432 B
    __shared__ __align__(16) unsigned short Al[2][64*32];   // 2 x  4096 B

    const int bid  = blockIdx.x;
    const int xcd  = bid & 7;
    const int rest = bid >> 3;
    const int gi   = rest >> 4;
    const int coff = rest & 15;
    const int g    = xcd + 8*gi;
    if (g >= NGROUP) return;
    const int chunk = g % NCHUNK;
    const int pt    = g / NCHUNK;
    const int c     = chunk*16 + coff;
    if (c >= CH) return;
    const int p0 = pt * BN;

    const int tid  = threadIdx.x;
    const int wv   = tid >> 6;
    const int lane = tid & 63;
    const int row  = lane & 15;
    const int kch  = lane >> 4;
    const int nb   = p0 + wv*48;

    const float* Wc          = W  + (size_t)c * ((size_t)PRED * SEQ);
    const unsigned short* Xc = xt + (size_t)c * RTOT;

    // ---- staging: per-lane global src w/ inverse swizzle; LDS dest linear ----
    auto stage = [&](int buf, int kk) {
#pragma unroll
        for (int i = 0; i < 6; ++i) {                 // B: 144 rows x 8 chunks
            const int slot = i*192 + tid;
            const int r    = slot >> 3;
            int sc = (slot & 7) ^ (r & 7);
            if (kk == 22) sc &= 3;                    // tail: clamp into s<720 (finite)
            gload16(Wc + (size_t)(p0 + r)*SEQ + kk*32 + sc*4,
                    &Bl[buf][(i*192 + (tid & ~63)) * 4]);
        }
#pragma unroll
        for (int i = 0; i < 2; ++i) {                 // A: 64 rows x 4 chunks (+dups)
            const int slot = (i*192 + tid) & 255;
            const int r    = slot >> 2;
            int sc = (slot & 3) ^ (r & 3);
            if (kk == 22) sc &= 1;
            gload16(Xc + (size_t)r*SEQ + kk*32 + sc*8,
                    &Al[buf][((i*192 + (tid & ~63)) & 255) * 8]);
        }
    };

    f32x4 acc[4][3] = {};

    auto compute = [&](int buf, bool tail) {
        short8 Af[4];
#pragma unroll
        for (int mi = 0; mi < 4; ++mi) {
            const int r2 = mi*16 + row;
            const int qa = kch ^ (r2 & 3);
            Af[mi] = *reinterpret_cast<const short8*>(&Al[buf][r2*32 + qa*8]);
        }
        short8 Bf[3];
#pragma unroll
        for (int ni = 0; ni < 3; ++ni) {
            const int r2  = wv*48 + ni*16 + row;
            const int qlo = (2*kch)     ^ (r2 & 7);
            const int qhi = (2*kch + 1) ^ (r2 & 7);
            f32x4 lo = *reinterpret_cast<const f32x4*>(&Bl[buf][r2*32 + qlo*4]);
            f32x4 hi = *reinterpret_cast<const f32x4*>(&Bl[buf][r2*32 + qhi*4]);
            short8 v;
#pragma unroll
            for (int j = 0; j < 4; ++j) { v[j] = bf16bits(lo[j]); v[4+j] = bf16bits(hi[j]); }
            Bf[ni] = v;
        }
        if (tail && kch >= 2) {        // zero invalid K range (clamped data is finite)
            short8 z = {};
            Bf[0] = z; Bf[1] = z; Bf[2] = z;
        }
#pragma unroll
        for (int mi = 0; mi < 4; ++mi)
#pragma unroll
            for (int ni = 0; ni < 3; ++ni)
                acc[mi][ni] = __builtin_amdgcn_mfma_f32_16x16x32_bf16(
                                  Af[mi], Bf[ni], acc[mi][ni], 0, 0, 0);
    };

    stage(0, 0);
    stage(1, 1);
    for (int k = 0; k < 22; ++k) {
        const int buf = k & 1;
        // wait stage(k) only — stage(k+1)'s 8 DMAs stay in flight
        asm volatile("s_waitcnt vmcnt(8)" ::: "memory");
        __builtin_amdgcn_sched_barrier(0);
        __builtin_amdgcn_s_barrier();                 // buf[k&1] ready for all waves

        short8 dummy;
        compute(buf, false);
        // all my LDS reads of buf done before anyone overwrites it
        asm volatile("s_waitcnt lgkmcnt(0)" ::: "memory");
        __builtin_amdgcn_sched_barrier(0);
        __builtin_amdgcn_s_barrier();
        if (k <= 20) stage(buf, k + 2);               // refill just-freed buffer
    }
    {   // peeled last step: k=22 (tail), buf 0
        asm volatile("s_waitcnt vmcnt(0)" ::: "memory");
        __builtin_amdgcn_sched_barrier(0);
        __builtin_amdgcn_s_barrier();
        compute(0, true);
    }

    // Epilogue. C/D map: col = lane&15, row = (lane>>4)*4 + reg.
    const int col   = lane & 15;
    const int rquad = lane >> 4;
    if (STAGED) {
        unsigned short* stg = (unsigned short*)outp;  // stage[c][p][b] bf16
#pragma unroll
        for (int ni = 0; ni < 3; ++ni) {
            const int p = nb + ni*16 + col;
            const float bv = bias[(size_t)c*PRED + p];
#pragma unroll
            for (int mi = 0; mi < 4; ++mi) {
                us4 u;
#pragma unroll
                for (int r = 0; r < 4; ++r)
                    u[r] = (unsigned short)bf16bits(acc[mi][ni][r] + bv);
                *reinterpret_cast<us4*>(
                    stg + ((size_t)c*PRED + p)*BATCH + mi*16 + rquad*4) = u;
            }
        }
    } else {
        float* outf = (float*)outp;
#pragma unroll
        for (int ni = 0; ni < 3; ++ni) {
            const int p = nb + ni*16 + col;
            const float bv = bias[(size_t)c*PRED + p];
#pragma unroll
            for (int mi = 0; mi < 4; ++mi)
#pragma unroll
                for (int r = 0; r < 4; ++r) {
                    const int b = mi*16 + rquad*4 + r;
                    outf[((size_t)b*PRED + p)*CH + c] = acc[mi][ni][r] + bv;
                }
        }
    }
}

// ---------------- fallback (no workspace): gather x directly, scattered stores ----------------
__global__ __launch_bounds__(192) void gemm_fallback_kernel(
        const float* __restrict__ W, const float* __restrict__ bias,
        const float* __restrict__ x, float* __restrict__ outp) {
    const int bid  = blockIdx.x;
    const int g    = (bid & 7) + 8*((bid >> 3) >> 4);
    const int coff = (bid >> 3) & 15;
    if (g >= NGROUP) return;
    const int c  = (g % NCHUNK)*16 + coff;
    if (c >= CH) return;
    const int p0 = (g / NCHUNK) * BN;
    const int tid = threadIdx.x, wv = tid >> 6, lane = tid & 63;
    const int row = lane & 15, kch = lane >> 4, nb = p0 + wv*48;
    const float* Wc = W + (size_t)c * ((size_t)PRED * SEQ);
    f32x4 acc[4][3] = {};
    for (int k = 0; k < 23; ++k) {
        const int kc = (k == 22) ? (kch & 1) : kch;
        const int s  = k*32 + kc*8;
        short8 Af[4], Bf[3];
#pragma unroll
        for (int mi = 0; mi < 4; ++mi) {
            short8 v;
#pragma unroll
            for (int j = 0; j < 8; ++j)
                v[j] = bf16bits(x[((size_t)(mi*16 + row)*SEQ + s + j)*CH + c]);
            Af[mi] = v;
        }
#pragma unroll
        for (int ni = 0; ni < 3; ++ni) {
            const float* p = Wc + (size_t)(nb + ni*16 + row)*SEQ + s;
            short8 v;
#pragma unroll
            for (int j = 0; j < 4; ++j) { v[j] = bf16bits(p[j]); v[4+j] = bf16bits(p[4+j]); }
            Bf[ni] = v;
        }
        if (k == 22 && kch >= 2) { short8 z = {}; Bf[0] = z; Bf[1] = z; Bf[2] = z; }
#pragma unroll
        for (int mi = 0; mi < 4; ++mi)
#pragma unroll
            for (int ni = 0; ni < 3; ++ni)
                acc[mi][ni] = __builtin_amdgcn_mfma_f32_16x16x32_bf16(
                                  Af[mi], Bf[ni], acc[mi][ni], 0, 0, 0);
    }
    const int col = lane & 15, rquad = lane >> 4;
#pragma unroll
    for (int ni = 0; ni < 3; ++ni) {
        const int p = nb + ni*16 + col;
        const float bv = bias[(size_t)c*PRED + p];
#pragma unroll
        for (int mi = 0; mi < 4; ++mi)
#pragma unroll
            for (int r = 0; r < 4; ++r)
                outp[((size_t)(mi*16 + rquad*4 + r)*PRED + p)*CH + c] = acc[mi][ni][r] + bv;
    }
}

// ---------------- unstage: stage[C][P][B] bf16 -> out[B][P][C] f32 ----------------
__global__ __launch_bounds__(256) void unstage_kernel(const unsigned short* __restrict__ stage,
                                                      float* __restrict__ out) {
    const int p  = blockIdx.x;
    const int c0 = blockIdx.y * 128;
    const int cn = (CH - c0 < 128) ? (CH - c0) : 128;
    __shared__ float tl[128][65];
    const int t = threadIdx.x;
    {
        const int b   = t & 63;
        const int ci0 = t >> 6;
        for (int ci = ci0; ci < cn; ci += 4) {
            unsigned short us = stage[((size_t)(c0+ci)*PRED + p)*BATCH + b];
            tl[ci][b] = __builtin_bit_cast(float, (u32)us << 16);
        }
    }
    __syncthreads();
    {
        const int cl = t & 127;
        const int b0 = t >> 7;
        if (cl < cn)
#pragma unroll
            for (int bb = b0; bb < BATCH; bb += 2)
                out[((size_t)bb*PRED + p)*CH + c0 + cl] = tl[cl][bb];
    }
}

extern "C" void kernel_launch(void* const* d_in, const int* in_sizes, int n_in,
                              void* d_out, int out_size, void* d_ws, size_t ws_size,
                              hipStream_t stream) {
    const float* x    = (const float*)d_in[0];
    const float* W    = (const float*)d_in[1];
    const float* bias = (const float*)d_in[2];
    float* out        = (float*)d_out;

    const size_t xt_bytes    = (size_t)CH * RTOT * sizeof(unsigned short);        // 29.6 MB
    const size_t stage_bytes = (size_t)CH * PRED * BATCH * sizeof(unsigned short);// 29.6 MB
    const int gemm_blocks = 8 * 14 * 16;  // covers 105 groups x 16 blocks (+dead pad)

    if (ws_size >= xt_bytes + stage_bytes) {
        unsigned short* xtp = (unsigned short*)d_ws;
        unsigned short* stg = (unsigned short*)((char*)d_ws + xt_bytes);
        xpose_kernel<<<dim3((RTOT/64) * 11), dim3(256), 0, stream>>>(x, xtp);
        gemm_lds_kernel<true><<<dim3(gemm_blocks), dim3(192), 0, stream>>>(
            W, bias, xtp, stg);
        unstage_kernel<<<dim3(PRED, 3), dim3(256), 0, stream>>>(stg, out);
    } else if (ws_size >= xt_bytes) {
        unsigned short* xtp = (unsigned short*)d_ws;
        xpose_kernel<<<dim3((RTOT/64) * 11), dim3(256), 0, stream>>>(x, xtp);
        gemm_lds_kernel<false><<<dim3(gemm_blocks), dim3(192), 0, stream>>>(
            W, bias, xtp, out);
    } else {
        gemm_fallback_kernel<<<dim3(gemm_blocks), dim3(192), 0, stream>>>(
            W, bias, x, out);
    }
}

// Round 5
// 217.731 us; speedup vs baseline: 1.9971x; 1.0344x over previous
//
#include <hip/hip_runtime.h>
#include <hip/hip_bf16.h>

// out[b,p,c] = sum_s x[b,s,c] * W[c,p,s] + bias[c,p]
// x: [64,720,321] f32, W: [321,720,720] f32, bias: [321,720] f32, out: [64,720,321] f32
// R5: DRAM-granularity attack. 1-wave blocks (BN=48, grid=321x15), BK=64 so each
//     staging DMA reads 256B contiguous per W-row (vs 128B before). Barrier-free
//     pipeline: all sync is per-wave counted vmcnt. LDS 40KB -> 4 blocks/CU.

#define SEQ   720
#define PRED  720
#define CH    321
#define BATCH 64
#define RTOT  (BATCH*SEQ)
#define BN1   48
#define NT1   15                /* 720/48 p-tiles */
#define BN    144               /* legacy fallback tiling */
#define NCHUNK 21
#define NGROUP (NCHUNK*5)

typedef __attribute__((ext_vector_type(8))) short short8;
typedef __attribute__((ext_vector_type(4))) float f32x4;
typedef __attribute__((ext_vector_type(4))) unsigned short us4;
typedef unsigned int u32;

__device__ __forceinline__ short bf16bits(float f) {
    return __builtin_bit_cast(short, __float2bfloat16(f));
}

// async global->LDS DMA, 16B/lane. LDS dest = wave-uniform base (+lane*16 by HW);
// global src is per-lane.
__device__ __forceinline__ void gload16(const void* g, void* l) {
    __builtin_amdgcn_global_load_lds((const __attribute__((address_space(1))) u32*)g,
                                     (__attribute__((address_space(3))) u32*)l, 16, 0, 0);
}

// ---------------- x transpose: [46080][321] f32 -> [321][46080] bf16 ----------------
__global__ __launch_bounds__(256) void xpose_kernel(const float* __restrict__ x,
                                                    unsigned short* __restrict__ xt) {
    __shared__ float tile[64][33];
    const int bid = blockIdx.x;
    const int rt = bid % (RTOT/64);
    const int ct = bid / (RTOT/64);
    const int r0 = rt*64, c0 = ct*32;
    const int t  = threadIdx.x;
    const int cl = t & 31, rl0 = t >> 5;
    const int cg = c0 + cl;
    if (cg < CH) {
#pragma unroll
        for (int j = 0; j < 8; ++j) {
            int rl = rl0 + j*8;
            tile[rl][cl] = x[(size_t)(r0+rl)*CH + cg];
        }
    }
    __syncthreads();
#pragma unroll
    for (int j = 0; j < 8; ++j) {
        int idx = t + j*256;
        int c_l = idx >> 6;
        int r_l = idx & 63;
        if (c0 + c_l < CH)
            xt[(size_t)(c0+c_l)*RTOT + r0 + r_l] = (unsigned short)bf16bits(tile[r_l][c_l]);
    }
}

// ---------------- per-channel GEMM: 1 wave/block, BK=64, barrier-free ----------------
// LDS B: [48 rows][16 x 16B chunks] f32; phys chunk q of row r holds logical q^(r&15)
//        (involution; preserves each row's 256B contiguous DRAM burst, permuted).
// LDS A: [64 rows][8 x 16B chunks] bf16; phys chunk q holds logical q^(r&7).
// Stage = 12 B-DMAs + 8 A-DMAs per K-step (each 1KB: 4 rows x 256B / 8 rows x 128B).
// K: 11 full steps of 64 + tail of 16 (clamped sources, kch>=2 B-frags zeroed).
template<bool STAGED>
__global__ __launch_bounds__(64) void gemm1w_kernel(
        const float* __restrict__ W, const float* __restrict__ bias,
        const unsigned short* __restrict__ xt, void* __restrict__ outp) {
    __shared__ __align__(16) float          Bl[2][BN1*64];   // 2 x 12 KB
    __shared__ __align__(16) unsigned short Al[2][64*64];    // 2 x  8 KB

    const int bid = blockIdx.x;
    const int c   = bid / NT1;
    const int pt  = bid % NT1;
    const int p0  = pt * BN1;
    const int lane = threadIdx.x & 63;
    const int row = lane & 15, kch = lane >> 4;

    const float* Wc          = W  + (size_t)c * ((size_t)PRED * SEQ);
    const unsigned short* Xc = xt + (size_t)c * RTOT;

    auto stage = [&](int buf, int kk) {
        const bool tail = (kk == 11);
#pragma unroll
        for (int i = 0; i < 12; ++i) {              // B: rows 4i..4i+3, 256B each
            const int r = 4*i + (lane >> 4);
            int sc = (lane & 15) ^ (r & 15);
            if (tail) sc &= 3;                      // clamp into s<720 (finite dup)
            gload16(Wc + (size_t)(p0 + r)*SEQ + kk*64 + sc*4, &Bl[buf][i*256]);
        }
#pragma unroll
        for (int i = 0; i < 8; ++i) {               // A: rows 8i..8i+7, 128B each (L3)
            const int r = 8*i + (lane >> 3);
            int sc = (lane & 7) ^ (r & 7);
            if (tail) sc &= 1;
            gload16(Xc + (size_t)r*SEQ + kk*64 + sc*8, &Al[buf][i*512]);
        }
    };

    f32x4 acc[4][3] = {};

    auto compute = [&](int buf, int s, bool ztail) {
        short8 Af[4];
#pragma unroll
        for (int mi = 0; mi < 4; ++mi) {
            const int r2 = mi*16 + row;
            const int qa = (s*4 + kch) ^ (r2 & 7);
            Af[mi] = *reinterpret_cast<const short8*>(&Al[buf][r2*64 + qa*8]);
        }
        short8 Bf[3];
#pragma unroll
        for (int ni = 0; ni < 3; ++ni) {
            const int r2  = ni*16 + row;
            const int qlo = (s*8 + 2*kch)     ^ (r2 & 15);
            const int qhi = (s*8 + 2*kch + 1) ^ (r2 & 15);
            f32x4 lo = *reinterpret_cast<const f32x4*>(&Bl[buf][r2*64 + qlo*4]);
            f32x4 hi = *reinterpret_cast<const f32x4*>(&Bl[buf][r2*64 + qhi*4]);
            short8 v;
#pragma unroll
            for (int j = 0; j < 4; ++j) { v[j] = bf16bits(lo[j]); v[4+j] = bf16bits(hi[j]); }
            Bf[ni] = v;
        }
        if (ztail && kch >= 2) {       // zero invalid K range (clamped data is finite)
            short8 z = {};
            Bf[0] = z; Bf[1] = z; Bf[2] = z;
        }
#pragma unroll
        for (int mi = 0; mi < 4; ++mi)
#pragma unroll
            for (int ni = 0; ni < 3; ++ni)
                acc[mi][ni] = __builtin_amdgcn_mfma_f32_16x16x32_bf16(
                                  Af[mi], Bf[ni], acc[mi][ni], 0, 0, 0);
    };

    stage(0, 0);
    stage(1, 1);
    for (int k = 0; k < 11; ++k) {
        const int buf = k & 1;
        // wait for stage(k)'s 20 DMAs; stage(k+1)'s 20 stay in flight
        asm volatile("s_waitcnt vmcnt(20)" ::: "memory");
        __builtin_amdgcn_sched_barrier(0);
        compute(buf, 0, false);
        compute(buf, 1, false);
        asm volatile("s_waitcnt lgkmcnt(0)" ::: "memory");   // my reads of buf done
        __builtin_amdgcn_sched_barrier(0);
        if (k <= 9) stage(buf, k + 2);               // refill just-freed buffer
    }
    {   // k=11 tail (16 cols), buf = 1
        asm volatile("s_waitcnt vmcnt(0)" ::: "memory");
        __builtin_amdgcn_sched_barrier(0);
        compute(1, 0, true);
    }

    // Epilogue. C/D map: col = lane&15, row = (lane>>4)*4 + reg.
    const int col   = lane & 15;
    const int rquad = lane >> 4;
    if (STAGED) {
        unsigned short* stg = (unsigned short*)outp;  // stage[c][p][b] bf16
#pragma unroll
        for (int ni = 0; ni < 3; ++ni) {
            const int p = p0 + ni*16 + col;
            const float bv = bias[(size_t)c*PRED + p];
#pragma unroll
            for (int mi = 0; mi < 4; ++mi) {
                us4 u;
#pragma unroll
                for (int r = 0; r < 4; ++r)
                    u[r] = (unsigned short)bf16bits(acc[mi][ni][r] + bv);
                *reinterpret_cast<us4*>(
                    stg + ((size_t)c*PRED + p)*BATCH + mi*16 + rquad*4) = u;
            }
        }
    } else {
        float* outf = (float*)outp;
#pragma unroll
        for (int ni = 0; ni < 3; ++ni) {
            const int p = p0 + ni*16 + col;
            const float bv = bias[(size_t)c*PRED + p];
#pragma unroll
            for (int mi = 0; mi < 4; ++mi)
#pragma unroll
                for (int r = 0; r < 4; ++r) {
                    const int b = mi*16 + rquad*4 + r;
                    outf[((size_t)b*PRED + p)*CH + c] = acc[mi][ni][r] + bv;
                }
        }
    }
}

// ---------------- fallback (no workspace): gather x directly, scattered stores ----------------
__global__ __launch_bounds__(192) void gemm_fallback_kernel(
        const float* __restrict__ W, const float* __restrict__ bias,
        const float* __restrict__ x, float* __restrict__ outp) {
    const int bid  = blockIdx.x;
    const int g    = (bid & 7) + 8*((bid >> 3) >> 4);
    const int coff = (bid >> 3) & 15;
    if (g >= NGROUP) return;
    const int c  = (g % NCHUNK)*16 + coff;
    if (c >= CH) return;
    const int p0 = (g / NCHUNK) * BN;
    const int tid = threadIdx.x, wv = tid >> 6, lane = tid & 63;
    const int row = lane & 15, kch = lane >> 4, nb = p0 + wv*48;
    const float* Wc = W + (size_t)c * ((size_t)PRED * SEQ);
    f32x4 acc[4][3] = {};
    for (int k = 0; k < 23; ++k) {
        const int kc = (k == 22) ? (kch & 1) : kch;
        const int s  = k*32 + kc*8;
        short8 Af[4], Bf[3];
#pragma unroll
        for (int mi = 0; mi < 4; ++mi) {
            short8 v;
#pragma unroll
            for (int j = 0; j < 8; ++j)
                v[j] = bf16bits(x[((size_t)(mi*16 + row)*SEQ + s + j)*CH + c]);
            Af[mi] = v;
        }
#pragma unroll
        for (int ni = 0; ni < 3; ++ni) {
            const float* p = Wc + (size_t)(nb + ni*16 + row)*SEQ + s;
            short8 v;
#pragma unroll
            for (int j = 0; j < 4; ++j) { v[j] = bf16bits(p[j]); v[4+j] = bf16bits(p[4+j]); }
            Bf[ni] = v;
        }
        if (k == 22 && kch >= 2) { short8 z = {}; Bf[0] = z; Bf[1] = z; Bf[2] = z; }
#pragma unroll
        for (int mi = 0; mi < 4; ++mi)
#pragma unroll
            for (int ni = 0; ni < 3; ++ni)
                acc[mi][ni] = __builtin_amdgcn_mfma_f32_16x16x32_bf16(
                                  Af[mi], Bf[ni], acc[mi][ni], 0, 0, 0);
    }
    const int col = lane & 15, rquad = lane >> 4;
#pragma unroll
    for (int ni = 0; ni < 3; ++ni) {
        const int p = nb + ni*16 + col;
        const float bv = bias[(size_t)c*PRED + p];
#pragma unroll
        for (int mi = 0; mi < 4; ++mi)
#pragma unroll
            for (int r = 0; r < 4; ++r)
                outp[((size_t)(mi*16 + rquad*4 + r)*PRED + p)*CH + c] = acc[mi][ni][r] + bv;
    }
}

// ---------------- unstage: stage[C][P][B] bf16 -> out[B][P][C] f32 ----------------
__global__ __launch_bounds__(256) void unstage_kernel(const unsigned short* __restrict__ stage,
                                                      float* __restrict__ out) {
    const int p  = blockIdx.x;
    const int c0 = blockIdx.y * 128;
    const int cn = (CH - c0 < 128) ? (CH - c0) : 128;
    __shared__ float tl[128][65];
    const int t = threadIdx.x;
    {
        const int b   = t & 63;
        const int ci0 = t >> 6;
        for (int ci = ci0; ci < cn; ci += 4) {
            unsigned short us = stage[((size_t)(c0+ci)*PRED + p)*BATCH + b];
            tl[ci][b] = __builtin_bit_cast(float, (u32)us << 16);
        }
    }
    __syncthreads();
    {
        const int cl = t & 127;
        const int b0 = t >> 7;
        if (cl < cn)
#pragma unroll
            for (int bb = b0; bb < BATCH; bb += 2)
                out[((size_t)bb*PRED + p)*CH + c0 + cl] = tl[cl][bb];
    }
}

extern "C" void kernel_launch(void* const* d_in, const int* in_sizes, int n_in,
                              void* d_out, int out_size, void* d_ws, size_t ws_size,
                              hipStream_t stream) {
    const float* x    = (const float*)d_in[0];
    const float* W    = (const float*)d_in[1];
    const float* bias = (const float*)d_in[2];
    float* out        = (float*)d_out;

    const size_t xt_bytes    = (size_t)CH * RTOT * sizeof(unsigned short);        // 29.6 MB
    const size_t stage_bytes = (size_t)CH * PRED * BATCH * sizeof(unsigned short);// 29.6 MB

    if (ws_size >= xt_bytes + stage_bytes) {
        unsigned short* xtp = (unsigned short*)d_ws;
        unsigned short* stg = (unsigned short*)((char*)d_ws + xt_bytes);
        xpose_kernel<<<dim3((RTOT/64) * 11), dim3(256), 0, stream>>>(x, xtp);
        gemm1w_kernel<true><<<dim3(CH * NT1), dim3(64), 0, stream>>>(W, bias, xtp, stg);
        unstage_kernel<<<dim3(PRED, 3), dim3(256), 0, stream>>>(stg, out);
    } else if (ws_size >= xt_bytes) {
        unsigned short* xtp = (unsigned short*)d_ws;
        xpose_kernel<<<dim3((RTOT/64) * 11), dim3(256), 0, stream>>>(x, xtp);
        gemm1w_kernel<false><<<dim3(CH * NT1), dim3(64), 0, stream>>>(W, bias, xtp, out);
    } else {
        gemm_fallback_kernel<<<dim3(8 * 14 * 16), dim3(192), 0, stream>>>(
            W, bias, x, out);
    }
}